// Round 1
// baseline (375.942 us; speedup 1.0000x reference)
//
#include <hip/hip_runtime.h>
#include <hip/hip_bf16.h>
#include <stdint.h>

// SimLinear: C[50,8192] = x[50,8192] @ W[8192,8192]^T + bias
// R5: delete the LDS staging of W entirely. W has ZERO reuse (read once),
// and the MFMA A-fragment (lane = m + 16q holds k-octet q of row m) is
// directly loadable from row-major W with 2x global_load_dwordx4 per lane.
// Each wave now owns a contiguous 2048-wide K-slice of the WG's 16 rows and
// streams it with a 2-block register double-buffer -> no barriers in the
// main loop, no vmcnt(0) drain, HBM pipe never empties. Cross-wave k-reduce
// epilogue (LDS, 16 KB) unchanged. B operand: packed bf16 x from L2 (XP).

#define K_DIM  8192
#define O_DIM  8192
#define BATCH  50
#define BPAD   64                 // padded batch (b>=50 zeroed in packed x)
#define ROWS   16                 // W rows (outputs) per WG
#define NWG    (O_DIM / ROWS)     // 512 WGs -> 2 per CU
#define KSLICE (K_DIM / 4)        // 2048 fp32 per wave
#define NSTEP  (KSLICE / 32)      // 64 k-steps of 32 fp32
#define U      2                  // steps per pipeline block
#define NBLK   (NSTEP / U)        // 32 blocks
#define XP_ELEMS ((size_t)(K_DIM / 8) * BPAD * 8)   // bf16 elems (1 MiB)

typedef __attribute__((ext_vector_type(8)))  __bf16 bf16x8;
typedef __attribute__((ext_vector_type(4)))  float  f32x4;
typedef __attribute__((ext_vector_type(4)))  int    i32x4;

// fp32 pair -> dword of two bf16 (round-half-up): +0x8000 then high halves.
__device__ __forceinline__ unsigned bfpair(float a, float b) {
    unsigned ua = __float_as_uint(a) + 0x8000u;
    unsigned ub = __float_as_uint(b) + 0x8000u;
    return __builtin_amdgcn_perm(ub, ua, 0x07060302u);  // [a.hi16, b.hi16]
}

__device__ __forceinline__ bf16x8 pack8(float4 lo, float4 hi) {
    i32x4 p;
    p.x = (int)bfpair(lo.x, lo.y);
    p.y = (int)bfpair(lo.z, lo.w);
    p.z = (int)bfpair(hi.x, hi.y);
    p.w = (int)bfpair(hi.z, hi.w);
    return __builtin_bit_cast(bf16x8, p);
}

// Pack x[50,8192] fp32 -> XP[k/8][b(64)][8] bf16 (B-fragment octet order,
// b>=50 zero). Thread i: b = i&63, ko = i>>6; writes 16 B at XP + i*8.
__global__ void pack_x(const float* __restrict__ X,
                       __hip_bfloat16* __restrict__ XP) {
    int i  = blockIdx.x * 256 + threadIdx.x;     // [0, 65536)
    int b  = i & 63;
    int ko = i >> 6;                             // k-octet [0, 1024)
    float4 z = {0.f, 0.f, 0.f, 0.f};
    float4 lo = z, hi = z;
    if (b < BATCH) {
        const float* xp = X + (size_t)b * K_DIM + (size_t)ko * 8;
        lo = *(const float4*)xp;
        hi = *(const float4*)(xp + 4);
    }
    *(bf16x8*)(XP + (size_t)i * 8) = pack8(lo, hi);
}

// Per-block register staging: U steps of A (2x float4/lane) + B (4x bf16x8).
struct AB {
    float4 a0[U], a1[U];
    bf16x8 b[U][4];
};

__device__ __forceinline__ void load_blk(AB& t, const float* __restrict__ wp,
                                         const __hip_bfloat16* __restrict__ xq,
                                         int blk) {
    #pragma unroll
    for (int j = 0; j < U; ++j) {
        const float* p = wp + (size_t)(blk * U + j) * 32;
        t.a0[j] = *(const float4*)p;
        t.a1[j] = *(const float4*)(p + 4);
    }
    #pragma unroll
    for (int j = 0; j < U; ++j)
        #pragma unroll
        for (int g = 0; g < 4; ++g)
            t.b[j][g] = *(const bf16x8*)
                (xq + ((size_t)(blk * U + j) * 4 * BPAD + g * 16) * 8);
}

__device__ __forceinline__ void comp_blk(const AB& t, f32x4* acc) {
    #pragma unroll
    for (int j = 0; j < U; ++j) {
        bf16x8 af = pack8(t.a0[j], t.a1[j]);
        #pragma unroll
        for (int g = 0; g < 4; ++g)
            acc[g] = __builtin_amdgcn_mfma_f32_16x16x32_bf16(
                         af, t.b[j][g], acc[g], 0, 0, 0);
    }
}

// WG = 16 W rows. Wave w streams K-slice [w*2048, (w+1)*2048) for all 16
// rows directly from global:
//   A[m=lane&15][k = s*32 + (lane>>4)*8 + 0..7]   (2x dwordx4, fp32->bf16)
//   B[k][n]: bf16x8 from packed x (L2-resident)
//   C/D: col=lane&15 (batch), row=(lane>>4)*4+reg (output row)
// Epilogue: cross-wave k-reduce in LDS, direct store + bias.
template<bool PACKED>
__global__ __launch_bounds__(256, 2) void simlinear_mfma(
        const float* __restrict__ X,
        const float* __restrict__ W,
        const __hip_bfloat16* __restrict__ XP,
        const float* __restrict__ bias,
        float* __restrict__ out) {
    __shared__ float red[4 * 1024];              // 16 KB epilogue reduce

    const int tid   = threadIdx.x;
    const int wave  = tid >> 6;
    const int lane  = tid & 63;
    const int l15   = lane & 15;
    const int q     = lane >> 4;                 // k-octet within step
    const int obase = blockIdx.x * ROWS;

    // Per-lane stream bases.
    const float* wp = W + (size_t)(obase + l15) * K_DIM + wave * KSLICE + q * 8;
    const __hip_bfloat16* xq =
        XP + ((size_t)(wave * (KSLICE / 8) + q) * BPAD + l15) * 8;

    f32x4 acc[4] = {};                           // 4 b-groups x 4 f32

    if (PACKED) {
        AB t0, t1;
        load_blk(t0, wp, xq, 0);
        #pragma unroll 1
        for (int blk = 0; blk < NBLK; blk += 2) {
            load_blk(t1, wp, xq, blk + 1);       // next block in flight
            comp_blk(t0, acc);
            if (blk + 2 < NBLK)
                load_blk(t0, wp, xq, blk + 2);
            comp_blk(t1, acc);
        }
    } else {
        // Fallback (workspace too small): build B from fp32 x on the fly.
        for (int s = 0; s < NSTEP; ++s) {
            const float* p = wp + (size_t)s * 32;
            bf16x8 af = pack8(*(const float4*)p, *(const float4*)(p + 4));
            const int ko = wave * (KSLICE / 8) + s * 4 + q;
            #pragma unroll
            for (int g = 0; g < 4; ++g) {
                const int b = g * 16 + l15;
                float4 z = {0.f, 0.f, 0.f, 0.f}, x0 = z, x1 = z;
                if (b < BATCH) {
                    const float* xp = X + (size_t)b * K_DIM + (size_t)ko * 8;
                    x0 = *(const float4*)xp;
                    x1 = *(const float4*)(xp + 4);
                }
                acc[g] = __builtin_amdgcn_mfma_f32_16x16x32_bf16(
                             af, pack8(x0, x1), acc[g], 0, 0, 0);
            }
        }
    }

    // ---- cross-wave reduce: red[w][b*16+m] ----
    #pragma unroll
    for (int g = 0; g < 4; ++g)
        #pragma unroll
        for (int r = 0; r < 4; ++r)
            red[wave * 1024 + (g * 16 + l15) * 16 + (q * 4 + r)] = acc[g][r];
    __syncthreads();

    #pragma unroll
    for (int it = 0; it < 4; ++it) {
        const int i = it * 256 + tid;            // [0,1024): b = i>>4, m = i&15
        const int b = i >> 4;
        const int m = i & 15;
        float s = red[i] + red[1024 + i] + red[2048 + i] + red[3072 + i];
        if (b < BATCH)
            out[(size_t)b * O_DIM + obase + m] = s + bias[obase + m];
    }
}

extern "C" void kernel_launch(void* const* d_in, const int* in_sizes, int n_in,
                              void* d_out, int out_size, void* d_ws, size_t ws_size,
                              hipStream_t stream) {
    const float* x    = (const float*)d_in[0];
    const float* w    = (const float*)d_in[1];
    const float* bias = (const float*)d_in[2];
    float* out = (float*)d_out;
    __hip_bfloat16* xp = (__hip_bfloat16*)d_ws;

    const bool packed = ws_size >= XP_ELEMS * sizeof(__hip_bfloat16);
    if (packed) {
        pack_x<<<(K_DIM / 8) * BPAD / 256, 256, 0, stream>>>(x, xp);
        simlinear_mfma<true><<<NWG, 256, 0, stream>>>(x, w, xp, bias, out);
    } else {
        simlinear_mfma<false><<<NWG, 256, 0, stream>>>(x, w, xp, bias, out);
    }
}